// Round 8
// baseline (69.196 us; speedup 1.0000x reference)
//
#include <hip/hip_runtime.h>
#include <hip/hip_bf16.h>
#include <math.h>

#define KC 32
#define DC 128
#define QC 16
#define NPTS 20000

// ws layout (bytes):
//   C2p[32] f32      @ 0
//   BT_HI[544*128] s @ 128       (rows 0..511 = G/sqrt2, 512..543 = w')
//   BT_LO[544*128] s @ 139392
//   XH[20000*128] s  @ 278656
//   XL[20000*128] s  @ 5398656
#define WS_C2P_B 0
#define WS_BTH_B 128
#define WS_BTL_B 139392
#define WS_XH_B  278656
#define WS_XL_B  5398656

typedef __attribute__((ext_vector_type(8)))  short bf16x8;
typedef __attribute__((ext_vector_type(16))) float f32x16;

// round-to-nearest-even bf16 split
static __device__ __forceinline__ short f2bf(float x) {
    union { float f; unsigned u; } v; v.f = x;
    unsigned r = v.u + 0x7fffu + ((v.u >> 16) & 1u);
    return (short)(r >> 16);
}
static __device__ __forceinline__ float bf2f(short h) {
    union { unsigned u; float f; } v; v.u = ((unsigned)(unsigned short)h) << 16;
    return v.f;
}

// role-split butterfly: sum a[r]^2 over the 16 lanes of this lane's 16-group;
// lane with (lane&15)==l4 returns the sum for reg r=l4.
static __device__ __forceinline__ float qreduce(const f32x16& a, int l4) {
    float v[16];
#pragma unroll
    for (int r = 0; r < 16; r++) v[r] = a[r]*a[r];
    float w[8];
    bool s0 = (l4 & 1) != 0;
#pragma unroll
    for (int j = 0; j < 8; j++) {
        float ta = v[2*j]   + __shfl_xor(v[2*j],   1, 64);
        float tb = v[2*j+1] + __shfl_xor(v[2*j+1], 1, 64);
        w[j] = s0 ? tb : ta;
    }
    float u[4];
    bool s1 = (l4 & 2) != 0;
#pragma unroll
    for (int j = 0; j < 4; j++) {
        float ta = w[2*j]   + __shfl_xor(w[2*j],   2, 64);
        float tb = w[2*j+1] + __shfl_xor(w[2*j+1], 2, 64);
        u[j] = s1 ? tb : ta;
    }
    float z[2];
    bool s2 = (l4 & 4) != 0;
#pragma unroll
    for (int j = 0; j < 2; j++) {
        float ta = u[2*j]   + __shfl_xor(u[2*j],   4, 64);
        float tb = u[2*j+1] + __shfl_xor(u[2*j+1], 4, 64);
        z[j] = s2 ? tb : ta;
    }
    bool s3 = (l4 & 8) != 0;
    float ta = z[0] + __shfl_xor(z[0], 8, 64);
    float tb = z[1] + __shfl_xor(z[1], 8, 64);
    return s3 ? tb : ta;
}

// ---------------------------------------------------------------------------
// Kernel 1: per-component Woodbury precompute (32 blocks).
// Emits G/sqrt(2) rows (bf16 hi/lo), w' rows, C2' constants.
// ---------------------------------------------------------------------------
__global__ __launch_bounds__(256) void mfa_pre(
    const float* __restrict__ log_pi, const float* __restrict__ mu,
    const float* __restrict__ Lam, const float* __restrict__ log_psi,
    float* __restrict__ c2p, short* __restrict__ btH, short* __restrict__ btL)
{
    int k = blockIdx.x, t = threadIdx.x;
    __shared__ float invpsiS[DC], muS[DC];
    __shared__ float lamR[DC*17];
    __shared__ float lamSc[DC*17];
    __shared__ float MS[QC*QC], LSm[QC*QC];
    __shared__ float invDS[QC];
    __shared__ float GT[QC*129];
    __shared__ float hS[QC];
    __shared__ float redS[4];
    __shared__ float hhS, ldS;

    float lp = 0.f, ipm = 0.f;
    if (t < DC) {
        float psi = expf(log_psi[t]) + 1e-5f + 1e-4f;
        float ip = 1.0f / psi;
        invpsiS[t] = ip;
        lp = logf(psi);
        float m = mu[k*DC + t];
        muS[t] = m;
        ipm = ip*m*m;
    }
    __syncthreads();
    for (int e = t; e < DC*QC; e += 256) {
        int d = e >> 4, q = e & 15;
        float lv = Lam[k*DC*QC + e];
        lamR[d*17 + q]  = lv;
        lamSc[d*17 + q] = lv * invpsiS[d];
    }
    __syncthreads();
    {   // M = I + Lam^T diag(invpsi) Lam
        int q = t >> 4, r = t & 15;
        float s0 = (q == r) ? 1.0f : 0.0f, s1 = 0.f, s2 = 0.f, s3 = 0.f;
#pragma unroll 1
        for (int d = 0; d < DC; d += 4) {
            s0 = fmaf(lamSc[(d+0)*17 + q], lamR[(d+0)*17 + r], s0);
            s1 = fmaf(lamSc[(d+1)*17 + q], lamR[(d+1)*17 + r], s1);
            s2 = fmaf(lamSc[(d+2)*17 + q], lamR[(d+2)*17 + r], s2);
            s3 = fmaf(lamSc[(d+3)*17 + q], lamR[(d+3)*17 + r], s3);
        }
        MS[q*QC + r] = (s0 + s1) + (s2 + s3);
    }
    __syncthreads();
    if (t < QC) {       // 16-lane shuffle Cholesky; lane i owns row i
        float m[QC], lrow[QC];
#pragma unroll
        for (int j = 0; j < QC; j++) m[j] = MS[t*QC + j];
#pragma unroll
        for (int j = 0; j < QC; j++) {
            float piv = __shfl(m[j], j, 16);
            float ljj = sqrtf(piv);
            float lij = m[j] / ljj;
            lrow[j] = lij;
#pragma unroll
            for (int r = j + 1; r < QC; r++)
                m[r] = fmaf(-lij, __shfl(lij, r, 16), m[r]);
        }
#pragma unroll
        for (int j = 0; j < QC; j++) LSm[t*QC + j] = lrow[j];
        invDS[t] = 1.0f / lrow[t];
        float ld = 2.0f * logf(lrow[t]);
        ld += __shfl_xor(ld, 1, 16);
        ld += __shfl_xor(ld, 2, 16);
        ld += __shfl_xor(ld, 4, 16);
        ld += __shfl_xor(ld, 8, 16);
        if (t == 0) ldS = ld;
    }
    __syncthreads();
    float g[QC];
    if (t < DC) {       // forward solve: column t of G
        float b[QC];
#pragma unroll
        for (int q = 0; q < QC; q++) b[q] = lamSc[t*17 + q];
#pragma unroll
        for (int i = 0; i < QC; i++) {
            float s = b[i];
#pragma unroll
            for (int x = 0; x < i; x++)
                s = fmaf(-LSm[i*QC + x], g[x], s);
            g[i] = s * invDS[i];
        }
        const float is2 = 0.70710678118654752f;
#pragma unroll
        for (int q = 0; q < QC; q++) {
            GT[q*129 + t] = g[q];
            float gs = g[q] * is2;                 // store G/sqrt(2)
            short hi = f2bf(gs);
            float hf = bf2f(hi);
            btH[(k*QC + q)*DC + t] = hi;
            btL[(k*QC + q)*DC + t] = f2bf(gs - hf);
        }
    }
    __syncthreads();
    if (t < QC) {       // h = G mu
        float s = 0.f;
        for (int d = 0; d < DC; d++)
            s = fmaf(GT[t*129 + d], muS[d], s);
        hS[t] = s;
        float hh = s*s;
        hh += __shfl_xor(hh, 1, 16);
        hh += __shfl_xor(hh, 2, 16);
        hh += __shfl_xor(hh, 4, 16);
        hh += __shfl_xor(hh, 8, 16);
        if (t == 0) hhS = hh;
    }
    {
        float a = lp, b2 = ipm;
#pragma unroll
        for (int off = 1; off < 64; off <<= 1) {
            a  += __shfl_xor(a, off, 64);
            b2 += __shfl_xor(b2, off, 64);
        }
        if (t == 0)  { redS[0] = a; redS[1] = b2; }
        if (t == 64) { redS[2] = a; redS[3] = b2; }
    }
    __syncthreads();
    if (t < DC) {       // w' = invpsi*mu - G^T h
        float gh = 0.f;
#pragma unroll
        for (int q = 0; q < QC; q++) gh = fmaf(g[q], hS[q], gh);
        float wp = invpsiS[t]*muS[t] - gh;
        short hi = f2bf(wp);
        float hf = bf2f(hi);
        btH[(512 + k)*DC + t] = hi;
        btL[(512 + k)*DC + t] = f2bf(wp - hf);
    }
    if (t == 0) {
        const float log2pi = 1.8378770664093453f;
        float slp = redS[0] + redS[2];
        float tv  = redS[1] + redS[3];
        c2p[k] = log_pi[k]
            - 0.5f*((float)DC*log2pi + slp + ldS + tv) + 0.5f*hhS;
    }
}

// ---------------------------------------------------------------------------
// Kernel 2 (mfa_conv): 313 blocks x 128 threads x 64 rows.
// Phase 1 (both waves): convert X rows to bf16 hi/lo, stash 0.5*s2 in LDS.
// Phase 2 (each wave, 32 rows): E[n,k] = w'_k.x_n + C2'_k - 0.5*s2_n via one
// 32x32 MFMA stack (B = w' panel from L2), written to out[n*32+k] coalesced.
// ---------------------------------------------------------------------------
__global__ __launch_bounds__(128) void mfa_conv(
    const float* __restrict__ X, const float* __restrict__ log_psi,
    const float* __restrict__ c2p,
    const short* __restrict__ btH, const short* __restrict__ btL,
    short* __restrict__ xH, short* __restrict__ xL, float* __restrict__ out)
{
    __shared__ float s2S[64];
    int t = threadIdx.x;
    int xb = blockIdx.x;               // 0..312, rows xb*64..+64
    int cseg = t & 15, rloc = t >> 4;  // rloc 0..7
    int c0 = cseg * 8;
    float is[8];
#pragma unroll
    for (int j = 0; j < 8; j++) {
        float psi = expf(log_psi[c0 + j]) + 1e-5f + 1e-4f;
        is[j] = 1.0f / psi;
    }
#pragma unroll
    for (int p = 0; p < 8; p++) {
        int r = xb*64 + p*8 + rloc;
        if (r < NPTS) {
            float xs[8];
            const float* xp = X + (size_t)r*DC + c0;
            *(float4*)&xs[0] = *(const float4*)xp;
            *(float4*)&xs[4] = *(const float4*)(xp + 4);
            bf16x8 hv, lv;
            float s2 = 0.f;
#pragma unroll
            for (int j = 0; j < 8; j++) {
                short hi = f2bf(xs[j]);
                float hf = bf2f(hi);
                hv[j] = hi;
                lv[j] = f2bf(xs[j] - hf);
                s2 = fmaf(xs[j]*is[j], xs[j], s2);
            }
            *(bf16x8*)(xH + (size_t)r*DC + c0) = hv;
            *(bf16x8*)(xL + (size_t)r*DC + c0) = lv;
            s2 += __shfl_xor(s2, 1, 64);
            s2 += __shfl_xor(s2, 2, 64);
            s2 += __shfl_xor(s2, 4, 64);
            s2 += __shfl_xor(s2, 8, 64);
            if (cseg == 0) s2S[p*8 + rloc] = 0.5f * s2;
        }
    }
    __syncthreads();                   // drains vmcnt -> xH/xL visible (L2)

    int w = t >> 6, l = t & 63;
    int m32 = l & 31, kh = l >> 5;
    int arow = min(xb*64 + w*32 + m32, NPTS - 1);
    const short* ap  = xH + (size_t)arow*DC + kh*8;
    const short* alp = xL + (size_t)arow*DC + kh*8;
    const short* bp  = btH + (size_t)(512 + m32)*DC + kh*8;
    const short* bq  = btL + (size_t)(512 + m32)*DC + kh*8;
    f32x16 acc = {};
#pragma unroll
    for (int ks = 0; ks < 8; ks++) {
        bf16x8 ah = *(const bf16x8*)(ap  + ks*16);
        bf16x8 al = *(const bf16x8*)(alp + ks*16);
        bf16x8 bh = *(const bf16x8*)(bp  + ks*16);
        bf16x8 bl = *(const bf16x8*)(bq  + ks*16);
        acc = __builtin_amdgcn_mfma_f32_32x32x16_bf16(ah, bh, acc, 0, 0, 0);
        acc = __builtin_amdgcn_mfma_f32_32x32x16_bf16(al, bh, acc, 0, 0, 0);
        acc = __builtin_amdgcn_mfma_f32_32x32x16_bf16(ah, bl, acc, 0, 0, 0);
    }
    float c2v = c2p[m32];
#pragma unroll
    for (int r = 0; r < 16; r++) {
        int rowl = w*32 + (r & 3) + 8*(r >> 2) + 4*kh;   // 0..63 local
        int grow = xb*64 + rowl;
        if (grow < NPTS)
            out[(size_t)grow*KC + m32] = acc[r] + c2v - s2S[rowl];
    }
}

// ---------------------------------------------------------------------------
// Kernel 3: pure-quad MFMA GEMM, 1-wave blocks, no LDS, no barrier.
// Grid 5056: low3=bid&7 (tile%8 -> XCD affinity), yb=(bid>>3)&7, tg=bid>>6;
// tile = tg*8+low3 (0..624, exactly 20000 rows). Wave: 32 rows x 4 comps.
// B fragments read straight from L2; 2-deep k-step pipeline; butterfly
// epilogue; out[n,k] += quad (E already there from mfa_conv).
// ---------------------------------------------------------------------------
__global__ __launch_bounds__(64, 4) void mfa_gemm(
    const short* __restrict__ xH, const short* __restrict__ xL,
    const short* __restrict__ btH, const short* __restrict__ btL,
    float* __restrict__ out)
{
    int bid = blockIdx.x;
    int low3 = bid & 7, yb = (bid >> 3) & 7, tg = bid >> 6;
    int tile = tg*8 + low3;
    if (tile >= 625) return;
    int l = threadIdx.x;
    int m32 = l & 31, kh = l >> 5, l4 = l & 15;

    int row = tile*32 + m32;                         // always < 20000
    const short* ap  = xH + (size_t)row*DC + kh*8;
    const short* alp = xL + (size_t)row*DC + kh*8;
    int pr = yb*64 + m32;
    const short* p0h = btH + (size_t)pr*DC + kh*8;
    const short* p0l = btL + (size_t)pr*DC + kh*8;
    const short* p1h = btH + (size_t)(pr + 32)*DC + kh*8;
    const short* p1l = btL + (size_t)(pr + 32)*DC + kh*8;

    // E RMW addresses + early loads
    int erow = tile*32 + (l4 & 3) + 8*(l4 >> 2) + 4*kh;
    int comp0 = yb*4 + ((l >> 4) & 1);
    float e0 = out[(size_t)erow*KC + comp0];
    float e1 = out[(size_t)erow*KC + comp0 + 2];

    bf16x8 ah[2], al[2], b0h[2], b0l[2], b1h[2], b1l[2];
#define LOADK(KS, S) { \
    ah[S]  = *(const bf16x8*)(ap  + (KS)*16); \
    al[S]  = *(const bf16x8*)(alp + (KS)*16); \
    b0h[S] = *(const bf16x8*)(p0h + (KS)*16); \
    b0l[S] = *(const bf16x8*)(p0l + (KS)*16); \
    b1h[S] = *(const bf16x8*)(p1h + (KS)*16); \
    b1l[S] = *(const bf16x8*)(p1l + (KS)*16); }

    f32x16 acc0 = {}, acc1 = {};
    LOADK(0, 0);
    LOADK(1, 1);
#define KSTEP(KS, S) { \
    __builtin_amdgcn_s_setprio(1); \
    acc0 = __builtin_amdgcn_mfma_f32_32x32x16_bf16(ah[S], b0h[S], acc0, 0, 0, 0); \
    acc1 = __builtin_amdgcn_mfma_f32_32x32x16_bf16(ah[S], b1h[S], acc1, 0, 0, 0); \
    acc0 = __builtin_amdgcn_mfma_f32_32x32x16_bf16(al[S], b0h[S], acc0, 0, 0, 0); \
    acc1 = __builtin_amdgcn_mfma_f32_32x32x16_bf16(al[S], b1h[S], acc1, 0, 0, 0); \
    acc0 = __builtin_amdgcn_mfma_f32_32x32x16_bf16(ah[S], b0l[S], acc0, 0, 0, 0); \
    acc1 = __builtin_amdgcn_mfma_f32_32x32x16_bf16(ah[S], b1l[S], acc1, 0, 0, 0); \
    __builtin_amdgcn_s_setprio(0); }

    KSTEP(0, 0); LOADK(2, 0);
    KSTEP(1, 1); LOADK(3, 1);
    KSTEP(2, 0); LOADK(4, 0);
    KSTEP(3, 1); LOADK(5, 1);
    KSTEP(4, 0); LOADK(6, 0);
    KSTEP(5, 1); LOADK(7, 1);
    KSTEP(6, 0);
    KSTEP(7, 1);
#undef KSTEP
#undef LOADK

    float q0 = qreduce(acc0, l4);
    float q1 = qreduce(acc1, l4);
    out[(size_t)erow*KC + comp0]     = e0 + q0;
    out[(size_t)erow*KC + comp0 + 2] = e1 + q1;
}

// ---------------------------------------------------------------------------
// Kernel 4: in-place logsumexp normalize + log-likelihood output.
// ---------------------------------------------------------------------------
__global__ __launch_bounds__(256) void mfa_norm(float* __restrict__ out)
{
    int n = blockIdx.x * 256 + threadIdx.x;
    if (n >= NPTS) return;
    float lr[KC];
#pragma unroll
    for (int i = 0; i < 8; i++)
        *(float4*)&lr[i*4] = *(const float4*)(out + (size_t)n*KC + i*4);
    float m = -1e30f;
#pragma unroll
    for (int k = 0; k < KC; k++) m = fmaxf(m, lr[k]);
    float s = 0.0f;
#pragma unroll
    for (int k = 0; k < KC; k++) s += expf(lr[k] - m);
    float ll = m + logf(s);
#pragma unroll
    for (int k = 0; k < KC; k++) lr[k] -= ll;
#pragma unroll
    for (int i = 0; i < 8; i++)
        *(float4*)(out + (size_t)n*KC + i*4) = *(const float4*)&lr[i*4];
    out[(size_t)NPTS*KC + n] = ll;
}

extern "C" void kernel_launch(void* const* d_in, const int* in_sizes, int n_in,
                              void* d_out, int out_size, void* d_ws, size_t ws_size,
                              hipStream_t stream)
{
    const float* X       = (const float*)d_in[0];
    const float* log_pi  = (const float*)d_in[1];
    const float* mu      = (const float*)d_in[2];
    const float* Lam     = (const float*)d_in[3];
    const float* log_psi = (const float*)d_in[4];
    float* out = (float*)d_out;
    char* wsb = (char*)d_ws;
    float* c2p = (float*)(wsb + WS_C2P_B);
    short* btH = (short*)(wsb + WS_BTH_B);
    short* btL = (short*)(wsb + WS_BTL_B);
    short* xH  = (short*)(wsb + WS_XH_B);
    short* xL  = (short*)(wsb + WS_XL_B);

    hipLaunchKernelGGL(mfa_pre, dim3(KC), dim3(256), 0, stream,
                       log_pi, mu, Lam, log_psi, c2p, btH, btL);
    hipLaunchKernelGGL(mfa_conv, dim3(313), dim3(128), 0, stream,
                       X, log_psi, c2p, btH, btL, xH, xL, out);
    hipLaunchKernelGGL(mfa_gemm, dim3(5056), dim3(64), 0, stream,
                       xH, xL, btH, btL, out);
    hipLaunchKernelGGL(mfa_norm, dim3(79), dim3(256), 0, stream, out);
}

// Round 9
// 46.711 us; speedup vs baseline: 1.4814x; 1.4814x over previous
//
#include <hip/hip_runtime.h>
#include <hip/hip_bf16.h>
#include <math.h>

#define KC 32
#define DC 128
#define QC 16
#define NPTS 20000

// ws layout (bytes):
//   C2p[32] f32      @ 0
//   BT_HI[544*128] s @ 128
//   BT_LO[544*128] s @ 139392
//   XH[1250*2048] s  @ 278656    (fragment-major: [tile16][ks][g4][m16][8])
//   XL[1250*2048] s  @ 5398656
//   S2H[20000] f32   @ 10518656  (pre-scaled by 0.5)
#define WS_C2P_B 0
#define WS_BTH_B 128
#define WS_BTL_B 139392
#define WS_XH_B  278656
#define WS_XL_B  5398656
#define WS_S2_B  10518656

typedef __attribute__((ext_vector_type(8))) short bf16x8;
typedef __attribute__((ext_vector_type(4))) float f32x4;

// round-to-nearest-even bf16 split
static __device__ __forceinline__ short f2bf(float x) {
    union { float f; unsigned u; } v; v.f = x;
    unsigned r = v.u + 0x7fffu + ((v.u >> 16) & 1u);
    return (short)(r >> 16);
}
static __device__ __forceinline__ float bf2f(short h) {
    union { unsigned u; float f; } v; v.u = ((unsigned)(unsigned short)h) << 16;
    return v.f;
}

// ---------------------------------------------------------------------------
// Kernel 1 (fused prep): blocks 0..31 per-component Woodbury precompute
// (G rows scaled by 1/sqrt(2), w' row, C2'); blocks 32+ convert 64 X rows
// each to bf16 hi/lo in FRAGMENT-MAJOR layout and store 0.5 * x^T Psi'^-1 x.
// Fragment-major: elem (row, col) -> plane[ (row>>4)*2048 + (col>>5)*512
//                                          + ((col&31)>>3)*128 + (row&15)*8 + (col&7) ]
// so a gemm wave's 64-lane A-fragment read is 1KB contiguous.
// ---------------------------------------------------------------------------
__global__ __launch_bounds__(256) void mfa_prep(
    const float* __restrict__ X, const float* __restrict__ log_pi,
    const float* __restrict__ mu, const float* __restrict__ Lam,
    const float* __restrict__ log_psi,
    float* __restrict__ c2p, short* __restrict__ btH, short* __restrict__ btL,
    short* __restrict__ xH, short* __restrict__ xL, float* __restrict__ s2g)
{
    int t = threadIdx.x;
    if (blockIdx.x >= KC) {
        // ---- conversion path: 64 rows per block, fragment-major writes ----
        int xb = blockIdx.x - KC;          // 0..312
        int cseg = t & 15, rloc = t >> 4;
        int c0 = cseg * 8;
        float is[8];
#pragma unroll
        for (int j = 0; j < 8; j++) {
            float psi = expf(log_psi[c0 + j]) + 1e-5f + 1e-4f;
            is[j] = 1.0f / psi;
        }
#pragma unroll
        for (int p = 0; p < 4; p++) {
            int r = xb*64 + p*16 + rloc;
            if (r < NPTS) {
                float xs[8];
                const float* xp = X + (size_t)r*DC + c0;
                *(float4*)&xs[0] = *(const float4*)xp;
                *(float4*)&xs[4] = *(const float4*)(xp + 4);
                bf16x8 hv, lv;
                float s2 = 0.f;
#pragma unroll
                for (int j = 0; j < 8; j++) {
                    short hi = f2bf(xs[j]);
                    float hf = bf2f(hi);
                    hv[j] = hi;
                    lv[j] = f2bf(xs[j] - hf);
                    s2 = fmaf(xs[j]*is[j], xs[j], s2);
                }
                // fragment-major address
                size_t fa = (size_t)(r >> 4)*2048 + (size_t)(cseg >> 2)*512
                          + (size_t)(cseg & 3)*128 + (size_t)(r & 15)*8;
                *(bf16x8*)(xH + fa) = hv;
                *(bf16x8*)(xL + fa) = lv;
                s2 += __shfl_xor(s2, 1, 16);
                s2 += __shfl_xor(s2, 2, 16);
                s2 += __shfl_xor(s2, 4, 16);
                s2 += __shfl_xor(s2, 8, 16);
                if (cseg == 0) s2g[r] = 0.5f * s2;
            }
        }
        return;
    }
    // ---- per-component path ----
    int k = blockIdx.x;
    __shared__ float invpsiS[DC], muS[DC];
    __shared__ float lamR[DC*17];        // Lam[d][q]
    __shared__ float lamSc[DC*17];       // Lam[d][q]*invpsi[d]
    __shared__ float MS[QC*QC], LSm[QC*QC];
    __shared__ float invDS[QC];
    __shared__ float GT[QC*129];
    __shared__ float hS[QC];
    __shared__ float redS[4];
    __shared__ float hhS, ldS;

    float lp = 0.f, ipm = 0.f;
    if (t < DC) {
        float psi = expf(log_psi[t]) + 1e-5f + 1e-4f;
        float ip = 1.0f / psi;
        invpsiS[t] = ip;
        lp = logf(psi);
        float m = mu[k*DC + t];
        muS[t] = m;
        ipm = ip*m*m;
    }
    __syncthreads();
    for (int e = t; e < DC*QC; e += 256) {
        int d = e >> 4, q = e & 15;
        float lv = Lam[k*DC*QC + e];
        lamR[d*17 + q]  = lv;
        lamSc[d*17 + q] = lv * invpsiS[d];
    }
    __syncthreads();
    {   // M = I + Lam^T diag(invpsi) Lam
        int q = t >> 4, r = t & 15;
        float s0 = (q == r) ? 1.0f : 0.0f, s1 = 0.f, s2 = 0.f, s3 = 0.f;
#pragma unroll 1
        for (int d = 0; d < DC; d += 4) {
            s0 = fmaf(lamSc[(d+0)*17 + q], lamR[(d+0)*17 + r], s0);
            s1 = fmaf(lamSc[(d+1)*17 + q], lamR[(d+1)*17 + r], s1);
            s2 = fmaf(lamSc[(d+2)*17 + q], lamR[(d+2)*17 + r], s2);
            s3 = fmaf(lamSc[(d+3)*17 + q], lamR[(d+3)*17 + r], s3);
        }
        MS[q*QC + r] = (s0 + s1) + (s2 + s3);
    }
    __syncthreads();
    if (t < QC) {       // 16-lane shuffle Cholesky; lane i owns row i
        float m[QC], lrow[QC];
#pragma unroll
        for (int j = 0; j < QC; j++) m[j] = MS[t*QC + j];
#pragma unroll
        for (int j = 0; j < QC; j++) {
            float piv = __shfl(m[j], j, 16);
            float ljj = sqrtf(piv);
            float lij = m[j] / ljj;
            lrow[j] = lij;
#pragma unroll
            for (int r = j + 1; r < QC; r++)
                m[r] = fmaf(-lij, __shfl(lij, r, 16), m[r]);
        }
#pragma unroll
        for (int j = 0; j < QC; j++) LSm[t*QC + j] = lrow[j];
        invDS[t] = 1.0f / lrow[t];
        float ld = 2.0f * logf(lrow[t]);
        ld += __shfl_xor(ld, 1, 16);
        ld += __shfl_xor(ld, 2, 16);
        ld += __shfl_xor(ld, 4, 16);
        ld += __shfl_xor(ld, 8, 16);
        if (t == 0) ldS = ld;
    }
    __syncthreads();
    float g[QC];
    if (t < DC) {       // forward solve: column t of G
        float b[QC];
#pragma unroll
        for (int q = 0; q < QC; q++) b[q] = lamSc[t*17 + q];
#pragma unroll
        for (int i = 0; i < QC; i++) {
            float s = b[i];
#pragma unroll
            for (int x = 0; x < i; x++)
                s = fmaf(-LSm[i*QC + x], g[x], s);
            g[i] = s * invDS[i];
        }
        const float is2 = 0.70710678118654752f;
#pragma unroll
        for (int q = 0; q < QC; q++) {
            GT[q*129 + t] = g[q];
            float gs = g[q] * is2;                 // store G/sqrt(2)
            short hi = f2bf(gs);
            float hf = bf2f(hi);
            btH[(k*QC + q)*DC + t] = hi;
            btL[(k*QC + q)*DC + t] = f2bf(gs - hf);
        }
    }
    __syncthreads();
    if (t < QC) {       // h = G mu
        float s = 0.f;
        for (int d = 0; d < DC; d++)
            s = fmaf(GT[t*129 + d], muS[d], s);
        hS[t] = s;
        float hh = s*s;
        hh += __shfl_xor(hh, 1, 16);
        hh += __shfl_xor(hh, 2, 16);
        hh += __shfl_xor(hh, 4, 16);
        hh += __shfl_xor(hh, 8, 16);
        if (t == 0) hhS = hh;
    }
    {
        float a = lp, b2 = ipm;
#pragma unroll
        for (int off = 1; off < 64; off <<= 1) {
            a  += __shfl_xor(a, off, 64);
            b2 += __shfl_xor(b2, off, 64);
        }
        if (t == 0)  { redS[0] = a; redS[1] = b2; }
        if (t == 64) { redS[2] = a; redS[3] = b2; }
    }
    __syncthreads();
    if (t < DC) {       // w' = invpsi*mu - G^T h
        float gh = 0.f;
#pragma unroll
        for (int q = 0; q < QC; q++) gh = fmaf(g[q], hS[q], gh);
        float wp = invpsiS[t]*muS[t] - gh;
        short hi = f2bf(wp);
        float hf = bf2f(hi);
        btH[(512 + k)*DC + t] = hi;
        btL[(512 + k)*DC + t] = f2bf(wp - hf);
    }
    if (t == 0) {
        const float log2pi = 1.8378770664093453f;
        float slp = redS[0] + redS[2];
        float tv  = redS[1] + redS[3];
        c2p[k] = log_pi[k]
            - 0.5f*((float)DC*log2pi + slp + ldS + tv) + 0.5f*hhS;
    }
}

// ---------------------------------------------------------------------------
// Kernel 2: MFMA GEMM (r5 structure, coalesced fragment-major A loads).
// 2504 linear blocks; yb = wg&7 (XCD-affine comp group of 4), xb = wg>>3
// (64-row tile). Block = 4 waves, each 16 rows x 5 N-tiles.
// LDS exactly 40KB (80 rows x 256B x hi/lo planes, XOR-swizzled).
// A fragments: wave-uniform base (xb*4+w clamped), 1KB contiguous per load.
// lr = C2' + w'.x - 0.5 s2 + ||(G/sqrt2) x||^2   (0.5s2 precomputed).
// ---------------------------------------------------------------------------
#define LH (80*256)      // 20480 bytes per plane

__global__ __launch_bounds__(256, 4) void mfa_gemm(
    const short* __restrict__ xH, const short* __restrict__ xL,
    const float* __restrict__ s2g, const float* __restrict__ c2p,
    const short* __restrict__ btH, const short* __restrict__ btL,
    float* __restrict__ out)
{
    __shared__ __align__(16) char lds[2*LH];     // 40960 B
    int t = threadIdx.x;
    int wg = blockIdx.x;
    int yb = wg & 7, xb = wg >> 3;

    // stage B panel: all loads issued before writes
    bf16x8 rh[5], rl[5];
#pragma unroll
    for (int i = 0; i < 5; i++) {
        int s = t + i*256;
        int row = s >> 4, seg = s & 15;
        int gr = (row < 64) ? (yb*64 + row) : (512 + yb*4 + ((row - 64) & 3));
        rh[i] = *(const bf16x8*)(btH + gr*DC + seg*8);
        rl[i] = *(const bf16x8*)(btL + gr*DC + seg*8);
    }

    int l = t & 63, w = t >> 6;
    int m16 = l & 15, g4 = l >> 4;
    int rb0 = xb*64 + w*16;

    // A fragments: fragment-major, wave-uniform clamped tile base ->
    // each load is a contiguous 1KB wave read.
    int tile16 = min(xb*4 + w, (NPTS >> 4) - 1);
    const short* ph = xH + (size_t)tile16*2048 + g4*128 + m16*8;
    const short* pl = xL + (size_t)tile16*2048 + g4*128 + m16*8;
    bf16x8 aH[4], aL[4];
#pragma unroll
    for (int ks = 0; ks < 4; ks++) {
        aH[ks] = *(const bf16x8*)(ph + ks*512);
        aL[ks] = *(const bf16x8*)(pl + ks*512);
    }
    float s2p = s2g[min(rb0 + m16, NPTS - 1)];

#pragma unroll
    for (int i = 0; i < 5; i++) {
        int s = t + i*256;
        int row = s >> 4, seg = s & 15;
        unsigned bo = ((unsigned)(row*256 + seg*16)) ^ ((unsigned)(row & 7) << 4);
        *(bf16x8*)(lds + bo)      = rh[i];
        *(bf16x8*)(lds + LH + bo) = rl[i];
    }
    __syncthreads();

    f32x4 acc[5];
#pragma unroll
    for (int i = 0; i < 5; i++) acc[i] = (f32x4){0.f, 0.f, 0.f, 0.f};
#pragma unroll
    for (int nt = 0; nt < 5; nt++) {
        int row = (nt < 4 ? nt*16 : 64) + m16;
        unsigned rbse = (unsigned)row << 8;
        unsigned sw = (unsigned)(row & 7) << 4;
#pragma unroll
        for (int ks = 0; ks < 4; ks++) {
            unsigned bo = (rbse + (unsigned)((ks*32 + g4*8)*2)) ^ sw;
            bf16x8 bh = *(const bf16x8*)(lds + bo);
            bf16x8 bl = *(const bf16x8*)(lds + LH + bo);
            acc[nt] = __builtin_amdgcn_mfma_f32_16x16x32_bf16(aH[ks], bh, acc[nt], 0, 0, 0);
            acc[nt] = __builtin_amdgcn_mfma_f32_16x16x32_bf16(aL[ks], bh, acc[nt], 0, 0, 0);
            acc[nt] = __builtin_amdgcn_mfma_f32_16x16x32_bf16(aH[ks], bl, acc[nt], 0, 0, 0);
        }
    }

#pragma unroll
    for (int nt = 0; nt < 4; nt++) {
        float c2v = c2p[yb*4 + nt];
#pragma unroll
        for (int j = 0; j < 4; j++) {
            float v = acc[nt][j]*acc[nt][j];
            v += __shfl_xor(v, 1, 64);
            v += __shfl_xor(v, 2, 64);
            v += __shfl_xor(v, 4, 64);
            v += __shfl_xor(v, 8, 64);                 // sum over q
            float pv  = __shfl(acc[4][j], (l & 48) | nt, 64);
            float s2j = __shfl(s2p, (l & 48) | (g4*4 + j), 64);
            float lr = c2v + pv - s2j + v;
            int row = rb0 + g4*4 + j;
            if (m16 == 0 && row < NPTS)
                out[(size_t)row*KC + yb*4 + nt] = lr;
        }
    }
}

// ---------------------------------------------------------------------------
// Kernel 3: in-place logsumexp normalize + log-likelihood output.
// ---------------------------------------------------------------------------
__global__ __launch_bounds__(256) void mfa_norm(float* __restrict__ out)
{
    int n = blockIdx.x * 256 + threadIdx.x;
    if (n >= NPTS) return;
    float lr[KC];
#pragma unroll
    for (int i = 0; i < 8; i++)
        *(float4*)&lr[i*4] = *(const float4*)(out + (size_t)n*KC + i*4);
    float m = -1e30f;
#pragma unroll
    for (int k = 0; k < KC; k++) m = fmaxf(m, lr[k]);
    float s = 0.0f;
#pragma unroll
    for (int k = 0; k < KC; k++) s += expf(lr[k] - m);
    float ll = m + logf(s);
#pragma unroll
    for (int k = 0; k < KC; k++) lr[k] -= ll;
#pragma unroll
    for (int i = 0; i < 8; i++)
        *(float4*)(out + (size_t)n*KC + i*4) = *(const float4*)&lr[i*4];
    out[(size_t)NPTS*KC + n] = ll;
}

extern "C" void kernel_launch(void* const* d_in, const int* in_sizes, int n_in,
                              void* d_out, int out_size, void* d_ws, size_t ws_size,
                              hipStream_t stream)
{
    const float* X       = (const float*)d_in[0];
    const float* log_pi  = (const float*)d_in[1];
    const float* mu      = (const float*)d_in[2];
    const float* Lam     = (const float*)d_in[3];
    const float* log_psi = (const float*)d_in[4];
    float* out = (float*)d_out;
    char* wsb = (char*)d_ws;
    float* c2p = (float*)(wsb + WS_C2P_B);
    short* btH = (short*)(wsb + WS_BTH_B);
    short* btL = (short*)(wsb + WS_BTL_B);
    short* xH  = (short*)(wsb + WS_XH_B);
    short* xL  = (short*)(wsb + WS_XL_B);
    float* s2g = (float*)(wsb + WS_S2_B);

    hipLaunchKernelGGL(mfa_prep, dim3(KC + 313), dim3(256), 0, stream,
                       X, log_pi, mu, Lam, log_psi, c2p, btH, btL, xH, xL, s2g);
    hipLaunchKernelGGL(mfa_gemm, dim3(2504), dim3(256), 0, stream,
                       xH, xL, s2g, c2p, btH, btL, out);
    hipLaunchKernelGGL(mfa_norm, dim3(79), dim3(256), 0, stream, out);
}

// Round 11
// 44.367 us; speedup vs baseline: 1.5596x; 1.0528x over previous
//
#include <hip/hip_runtime.h>
#include <hip/hip_bf16.h>
#include <math.h>

#define KC 32
#define DC 128
#define QC 16
#define NPTS 20000

// ws layout (bytes):
//   c2p[32] f32        @ 0
//   btG[544*128] bf16  @ 128     (rows 0..511 = G/sqrt2, 512..543 = w'; single plane)
//   s2h[20000] f32     @ 139392  (0.5 * x^T invpsi x)
//   XH[1250*2048] s    @ 219520  (fragment-major)
//   XL[1250*2048] s    @ 5339520
#define WS_C2P_B 0
#define WS_BTG_B 128
#define WS_S2_B  139392
#define WS_XH_B  219520
#define WS_XL_B  5339520

typedef __attribute__((ext_vector_type(8))) short bf16x8;
typedef __attribute__((ext_vector_type(4))) float f32x4;

// round-to-nearest-even bf16 split
static __device__ __forceinline__ short f2bf(float x) {
    union { float f; unsigned u; } v; v.f = x;
    unsigned r = v.u + 0x7fffu + ((v.u >> 16) & 1u);
    return (short)(r >> 16);
}
static __device__ __forceinline__ float bf2f(short h) {
    union { unsigned u; float f; } v; v.u = ((unsigned)(unsigned short)h) << 16;
    return v.f;
}

// ---------------------------------------------------------------------------
// Kernel 1 (fused prep): blocks 0..31 per-component Woodbury precompute
// (G/sqrt2 rows + w' row, single-plane bf16; C2'); blocks 32+ convert 64 X
// rows each to bf16 hi/lo fragment-major and store 0.5 * x^T Psi'^-1 x.
// ---------------------------------------------------------------------------
__global__ __launch_bounds__(256) void mfa_prep(
    const float* __restrict__ X, const float* __restrict__ log_pi,
    const float* __restrict__ mu, const float* __restrict__ Lam,
    const float* __restrict__ log_psi,
    float* __restrict__ c2p, short* __restrict__ btG,
    short* __restrict__ xH, short* __restrict__ xL, float* __restrict__ s2g)
{
    int t = threadIdx.x;
    if (blockIdx.x >= KC) {
        // ---- conversion path: 64 rows per block, fragment-major writes ----
        int xb = blockIdx.x - KC;          // 0..312
        int cseg = t & 15, rloc = t >> 4;
        int c0 = cseg * 8;
        float is[8];
#pragma unroll
        for (int j = 0; j < 8; j++) {
            float psi = expf(log_psi[c0 + j]) + 1e-5f + 1e-4f;
            is[j] = 1.0f / psi;
        }
#pragma unroll
        for (int p = 0; p < 4; p++) {
            int r = xb*64 + p*16 + rloc;
            if (r < NPTS) {
                float xs[8];
                const float* xp = X + (size_t)r*DC + c0;
                *(float4*)&xs[0] = *(const float4*)xp;
                *(float4*)&xs[4] = *(const float4*)(xp + 4);
                bf16x8 hv, lv;
                float s2 = 0.f;
#pragma unroll
                for (int j = 0; j < 8; j++) {
                    short hi = f2bf(xs[j]);
                    float hf = bf2f(hi);
                    hv[j] = hi;
                    lv[j] = f2bf(xs[j] - hf);
                    s2 = fmaf(xs[j]*is[j], xs[j], s2);
                }
                size_t fa = (size_t)(r >> 4)*2048 + (size_t)(cseg >> 2)*512
                          + (size_t)(cseg & 3)*128 + (size_t)(r & 15)*8;
                *(bf16x8*)(xH + fa) = hv;
                *(bf16x8*)(xL + fa) = lv;
                s2 += __shfl_xor(s2, 1, 16);
                s2 += __shfl_xor(s2, 2, 16);
                s2 += __shfl_xor(s2, 4, 16);
                s2 += __shfl_xor(s2, 8, 16);
                if (cseg == 0) s2g[r] = 0.5f * s2;
            }
        }
        return;
    }
    // ---- per-component Woodbury path ----
    int k = blockIdx.x;
    __shared__ float invpsiS[DC], muS[DC];
    __shared__ float lamR[DC*17];        // Lam[d][q]
    __shared__ float lamSc[DC*17];       // Lam[d][q]*invpsi[d]
    __shared__ float MS[QC*QC], LSm[QC*QC];
    __shared__ float invDS[QC];
    __shared__ float GT[QC*129];
    __shared__ float hS[QC];
    __shared__ float redS[4];
    __shared__ float hhS, ldS;

    float lp = 0.f, ipm = 0.f;
    if (t < DC) {
        float psi = expf(log_psi[t]) + 1e-5f + 1e-4f;
        float ip = 1.0f / psi;
        invpsiS[t] = ip;
        lp = logf(psi);
        float m = mu[k*DC + t];
        muS[t] = m;
        ipm = ip*m*m;
    }
    __syncthreads();
    for (int e = t; e < DC*QC; e += 256) {
        int d = e >> 4, q = e & 15;
        float lv = Lam[k*DC*QC + e];
        lamR[d*17 + q]  = lv;
        lamSc[d*17 + q] = lv * invpsiS[d];
    }
    __syncthreads();
    {   // M = I + Lam^T diag(invpsi) Lam
        int q = t >> 4, r = t & 15;
        float s0 = (q == r) ? 1.0f : 0.0f, s1 = 0.f, s2 = 0.f, s3 = 0.f;
#pragma unroll 1
        for (int d = 0; d < DC; d += 4) {
            s0 = fmaf(lamSc[(d+0)*17 + q], lamR[(d+0)*17 + r], s0);
            s1 = fmaf(lamSc[(d+1)*17 + q], lamR[(d+1)*17 + r], s1);
            s2 = fmaf(lamSc[(d+2)*17 + q], lamR[(d+2)*17 + r], s2);
            s3 = fmaf(lamSc[(d+3)*17 + q], lamR[(d+3)*17 + r], s3);
        }
        MS[q*QC + r] = (s0 + s1) + (s2 + s3);
    }
    __syncthreads();
    if (t < QC) {       // 16-lane shuffle Cholesky; lane i owns row i
        float m[QC], lrow[QC];
#pragma unroll
        for (int j = 0; j < QC; j++) m[j] = MS[t*QC + j];
#pragma unroll
        for (int j = 0; j < QC; j++) {
            float piv = __shfl(m[j], j, 16);
            float ljj = sqrtf(piv);
            float lij = m[j] / ljj;
            lrow[j] = lij;
#pragma unroll
            for (int r = j + 1; r < QC; r++)
                m[r] = fmaf(-lij, __shfl(lij, r, 16), m[r]);
        }
#pragma unroll
        for (int j = 0; j < QC; j++) LSm[t*QC + j] = lrow[j];
        invDS[t] = 1.0f / lrow[t];
        float ld = 2.0f * logf(lrow[t]);
        ld += __shfl_xor(ld, 1, 16);
        ld += __shfl_xor(ld, 2, 16);
        ld += __shfl_xor(ld, 4, 16);
        ld += __shfl_xor(ld, 8, 16);
        if (t == 0) ldS = ld;
    }
    __syncthreads();
    float g[QC];
    if (t < DC) {       // forward solve: column t of G
        float b[QC];
#pragma unroll
        for (int q = 0; q < QC; q++) b[q] = lamSc[t*17 + q];
#pragma unroll
        for (int i = 0; i < QC; i++) {
            float s = b[i];
#pragma unroll
            for (int x = 0; x < i; x++)
                s = fmaf(-LSm[i*QC + x], g[x], s);
            g[i] = s * invDS[i];
        }
        const float is2 = 0.70710678118654752f;
#pragma unroll
        for (int q = 0; q < QC; q++) {
            GT[q*129 + t] = g[q];
            btG[(k*QC + q)*DC + t] = f2bf(g[q] * is2);   // G/sqrt2, single plane
        }
    }
    __syncthreads();
    if (t < QC) {       // h = G mu
        float s = 0.f;
        for (int d = 0; d < DC; d++)
            s = fmaf(GT[t*129 + d], muS[d], s);
        hS[t] = s;
        float hh = s*s;
        hh += __shfl_xor(hh, 1, 16);
        hh += __shfl_xor(hh, 2, 16);
        hh += __shfl_xor(hh, 4, 16);
        hh += __shfl_xor(hh, 8, 16);
        if (t == 0) hhS = hh;
    }
    {
        float a = lp, b2 = ipm;
#pragma unroll
        for (int off = 1; off < 64; off <<= 1) {
            a  += __shfl_xor(a, off, 64);
            b2 += __shfl_xor(b2, off, 64);
        }
        if (t == 0)  { redS[0] = a; redS[1] = b2; }
        if (t == 64) { redS[2] = a; redS[3] = b2; }
    }
    __syncthreads();
    if (t < DC) {       // w' = invpsi*mu - G^T h  (single-plane bf16)
        float gh = 0.f;
#pragma unroll
        for (int q = 0; q < QC; q++) gh = fmaf(g[q], hS[q], gh);
        float wp = invpsiS[t]*muS[t] - gh;
        btG[(512 + k)*DC + t] = f2bf(wp);
    }
    if (t == 0) {
        const float log2pi = 1.8378770664093453f;
        float slp = redS[0] + redS[2];
        float tv  = redS[1] + redS[3];
        c2p[k] = log_pi[k]
            - 0.5f*((float)DC*log2pi + slp + ldS + tv) + 0.5f*hhS;
    }
}

// ---------------------------------------------------------------------------
// Kernel 2: MFMA GEMM (r9 structure, single-plane B).
// 2504 blocks; yb = wg&7 (comp group of 4), xb = wg>>3 (64-row tile).
// Block = 4 waves, each 16 rows x 5 N-tiles (4 G-tiles + w'-tile).
// LDS = 80 rows x 256B single bf16 plane = 20 KB, XOR-swizzled.
// A = precomputed hi/lo fragment-major (1 KB coalesced wave loads).
// lr = C2' + w'.x - 0.5 s2 + ||(G/sqrt2) x||^2   (0.5s2 precomputed).
// ---------------------------------------------------------------------------
#define LH 20480     // 80*256 bytes

__global__ __launch_bounds__(256, 4) void mfa_gemm(
    const short* __restrict__ xH, const short* __restrict__ xL,
    const float* __restrict__ s2g, const float* __restrict__ c2p,
    const short* __restrict__ btG, float* __restrict__ out)
{
    __shared__ __align__(16) char lds[LH];
    int t = threadIdx.x;
    int wg = blockIdx.x;
    int yb = wg & 7, xb = wg >> 3;

    // stage B panel (single plane): 1280 chunks, 5 per thread
    bf16x8 rh[5];
#pragma unroll
    for (int i = 0; i < 5; i++) {
        int s = t + i*256;
        int row = s >> 4, seg = s & 15;
        int gr = (row < 64) ? (yb*64 + row) : (512 + yb*4 + ((row - 64) & 3));
        rh[i] = *(const bf16x8*)(btG + gr*DC + seg*8);
    }

    int l = t & 63, w = t >> 6;
    int m16 = l & 15, g4 = l >> 4;
    int rb0 = xb*64 + w*16;

    // A fragments: fragment-major hi/lo, wave-uniform clamped tile base
    int tile16 = min(xb*4 + w, (NPTS >> 4) - 1);
    const short* ph = xH + (size_t)tile16*2048 + g4*128 + m16*8;
    const short* pl = xL + (size_t)tile16*2048 + g4*128 + m16*8;
    bf16x8 aH[4], aL[4];
#pragma unroll
    for (int ks = 0; ks < 4; ks++) {
        aH[ks] = *(const bf16x8*)(ph + ks*512);
        aL[ks] = *(const bf16x8*)(pl + ks*512);
    }
    float s2p = s2g[min(rb0 + m16, NPTS - 1)];

    // swizzled ds_writes
#pragma unroll
    for (int i = 0; i < 5; i++) {
        int s = t + i*256;
        int row = s >> 4, seg = s & 15;
        unsigned bo = ((unsigned)(row*256 + seg*16)) ^ ((unsigned)(row & 7) << 4);
        *(bf16x8*)(lds + bo) = rh[i];
    }
    __syncthreads();

    f32x4 acc[5];
#pragma unroll
    for (int i = 0; i < 5; i++) acc[i] = (f32x4){0.f, 0.f, 0.f, 0.f};
#pragma unroll
    for (int nt = 0; nt < 5; nt++) {
        int row = (nt < 4 ? nt*16 : 64) + m16;
        unsigned rbse = (unsigned)row << 8;
        unsigned sw = (unsigned)(row & 7) << 4;
#pragma unroll
        for (int ks = 0; ks < 4; ks++) {
            unsigned bo = (rbse + (unsigned)((ks*32 + g4*8)*2)) ^ sw;
            bf16x8 bh = *(const bf16x8*)(lds + bo);
            acc[nt] = __builtin_amdgcn_mfma_f32_16x16x32_bf16(aH[ks], bh, acc[nt], 0, 0, 0);
            acc[nt] = __builtin_amdgcn_mfma_f32_16x16x32_bf16(aL[ks], bh, acc[nt], 0, 0, 0);
        }
    }

#pragma unroll
    for (int nt = 0; nt < 4; nt++) {
        float c2v = c2p[yb*4 + nt];
#pragma unroll
        for (int j = 0; j < 4; j++) {
            float v = acc[nt][j]*acc[nt][j];
            v += __shfl_xor(v, 1, 64);
            v += __shfl_xor(v, 2, 64);
            v += __shfl_xor(v, 4, 64);
            v += __shfl_xor(v, 8, 64);                 // sum over q
            float pv  = __shfl(acc[4][j], (l & 48) | nt, 64);
            float s2j = __shfl(s2p, (l & 48) | (g4*4 + j), 64);
            float lr = c2v + pv - s2j + v;
            int row = rb0 + g4*4 + j;
            if (m16 == 0 && row < NPTS)
                out[(size_t)row*KC + yb*4 + nt] = lr;
        }
    }
}

// ---------------------------------------------------------------------------
// Kernel 3: in-place logsumexp normalize + log-likelihood output.
// ---------------------------------------------------------------------------
__global__ __launch_bounds__(256) void mfa_norm(float* __restrict__ out)
{
    int n = blockIdx.x * 256 + threadIdx.x;
    if (n >= NPTS) return;
    float lr[KC];
#pragma unroll
    for (int i = 0; i < 8; i++)
        *(float4*)&lr[i*4] = *(const float4*)(out + (size_t)n*KC + i*4);
    float m = -1e30f;
#pragma unroll
    for (int k = 0; k < KC; k++) m = fmaxf(m, lr[k]);
    float s = 0.0f;
#pragma unroll
    for (int k = 0; k < KC; k++) s += expf(lr[k] - m);
    float ll = m + logf(s);
#pragma unroll
    for (int k = 0; k < KC; k++) lr[k] -= ll;
#pragma unroll
    for (int i = 0; i < 8; i++)
        *(float4*)(out + (size_t)n*KC + i*4) = *(const float4*)&lr[i*4];
    out[(size_t)NPTS*KC + n] = ll;
}

extern "C" void kernel_launch(void* const* d_in, const int* in_sizes, int n_in,
                              void* d_out, int out_size, void* d_ws, size_t ws_size,
                              hipStream_t stream)
{
    const float* X       = (const float*)d_in[0];
    const float* log_pi  = (const float*)d_in[1];
    const float* mu      = (const float*)d_in[2];
    const float* Lam     = (const float*)d_in[3];
    const float* log_psi = (const float*)d_in[4];
    float* out = (float*)d_out;
    char* wsb = (char*)d_ws;
    float* c2p = (float*)(wsb + WS_C2P_B);
    short* btG = (short*)(wsb + WS_BTG_B);
    float* s2g = (float*)(wsb + WS_S2_B);
    short* xH  = (short*)(wsb + WS_XH_B);
    short* xL  = (short*)(wsb + WS_XL_B);

    hipLaunchKernelGGL(mfa_prep, dim3(KC + 313), dim3(256), 0, stream,
                       X, log_pi, mu, Lam, log_psi, c2p, btG, xH, xL, s2g);
    hipLaunchKernelGGL(mfa_gemm, dim3(2504), dim3(256), 0, stream,
                       xH, xL, s2g, c2p, btG, out);
    hipLaunchKernelGGL(mfa_norm, dim3(79), dim3(256), 0, stream, out);
}